// Round 1
// baseline (3181.101 us; speedup 1.0000x reference)
//
#include <hip/hip_runtime.h>
#include <math.h>

namespace {

constexpr int NB = 32;     // batch
constexpr int L  = 512;
constexpr int E  = 768;
constexpr int F  = 512;
constexpr float EPS = 1e-7f;

constexpr int TBM = 64, TBN = 64, TBK = 16;

__device__ __forceinline__ float waveSum(float v) {
#pragma unroll
    for (int off = 32; off > 0; off >>= 1) v += __shfl_down(v, off, 64);
    return v;
}
__device__ __forceinline__ float waveMax(float v) {
#pragma unroll
    for (int off = 32; off > 0; off >>= 1) v = fmaxf(v, __shfl_down(v, off, 64));
    return v;
}

// ---------------- conv1d (K=3, SAME, per-batch zero pad) as GEMM + bias + relu ---
// Out[m, f] = relu(bias[f] + sum_{kk,e} X[b, l+kk-1, e] * W[kk,e,f]),  m = b*L+l
__global__ __launch_bounds__(256)
void conv_gemm_relu(const float* __restrict__ X,    // [NB,L,E]
                    const float* __restrict__ W,    // [3,E,Cout]
                    const float* __restrict__ bias, // [Cout]
                    float* __restrict__ Out,        // row stride ldo
                    int Cout, int ldo)
{
    __shared__ float As[TBK][TBM];
    __shared__ float Bs[TBK][TBN];
    const int tid = threadIdx.x;
    const int tx = tid & 15, ty = tid >> 4;
    const int m0 = blockIdx.y * TBM;
    const int f0 = blockIdx.x * TBN;
    const int mi = tid >> 2;
    const int pe = (tid & 3) << 2;
    const int pi = tid >> 4;
    const int fi = (tid & 15) << 2;

    float acc[4][4] = {};

    for (int kk = 0; kk < 3; ++kk) {
        const int m = m0 + mi;
        const int b = m >> 9;
        const int l = (m & (L - 1)) + kk - 1;
        const bool valid = (l >= 0) && (l < L);
        const float* xrow = X + ((size_t)b * L + (valid ? l : 0)) * E;
        for (int e0 = 0; e0 < E; e0 += TBK) {
            float4 av = make_float4(0.f, 0.f, 0.f, 0.f);
            if (valid) av = *(const float4*)(xrow + e0 + pe);
            As[pe + 0][mi] = av.x;
            As[pe + 1][mi] = av.y;
            As[pe + 2][mi] = av.z;
            As[pe + 3][mi] = av.w;
            *(float4*)&Bs[pi][fi] =
                *(const float4*)(W + ((size_t)kk * E + e0 + pi) * Cout + f0 + fi);
            __syncthreads();
#pragma unroll
            for (int p = 0; p < TBK; ++p) {
                const float4 a4 = *(const float4*)&As[p][ty << 2];
                const float4 b4 = *(const float4*)&Bs[p][tx << 2];
                const float ar[4] = {a4.x, a4.y, a4.z, a4.w};
                const float br[4] = {b4.x, b4.y, b4.z, b4.w};
#pragma unroll
                for (int i = 0; i < 4; ++i)
#pragma unroll
                    for (int j = 0; j < 4; ++j) acc[i][j] += ar[i] * br[j];
            }
            __syncthreads();
        }
    }
#pragma unroll
    for (int i = 0; i < 4; ++i) {
        const int m = m0 + (ty << 2) + i;
        const int f = f0 + (tx << 2);
        float4 o;
        o.x = fmaxf(acc[i][0] + bias[f + 0], 0.f);
        o.y = fmaxf(acc[i][1] + bias[f + 1], 0.f);
        o.z = fmaxf(acc[i][2] + bias[f + 2], 0.f);
        o.w = fmaxf(acc[i][3] + bias[f + 3], 0.f);
        *(float4*)&Out[(size_t)m * ldo + f] = o;
    }
}

// ---------------- inverse L2 norm of each row ----------------
__global__ __launch_bounds__(256)
void inv_l2norm(const float* __restrict__ Xp, int len, int ld, float* __restrict__ inv)
{
    __shared__ float red[4];
    const int m = blockIdx.x;
    const float* row = Xp + (size_t)m * ld;
    float s = 0.f;
    for (int h = threadIdx.x; h < len; h += 256) { const float v = row[h]; s += v * v; }
    s = waveSum(s);
    const int lane = threadIdx.x & 63, wid = threadIdx.x >> 6;
    if (lane == 0) red[wid] = s;
    __syncthreads();
    if (threadIdx.x == 0)
        inv[m] = 1.0f / sqrtf(fmaxf(red[0] + red[1] + red[2] + red[3], 1e-12f));
}

// ---------------- batched C = (A · B^T) * sa[i] * sb[j] ----------------
__global__ __launch_bounds__(256)
void gemm_nt(const float* __restrict__ A, int lda, long long sA,
             const float* __restrict__ Bm, int ldb, long long sB,
             float* __restrict__ Cc, int ldc, long long sC, int K,
             const float* __restrict__ sa, const float* __restrict__ sb)
{
    __shared__ float As[TBK][TBM];
    __shared__ float Bs[TBK][TBN];
    const int bz = blockIdx.z;
    const float* Ab = A + (size_t)bz * sA;
    const float* Bb = Bm + (size_t)bz * sB;
    float* Cb = Cc + (size_t)bz * sC;
    const int tid = threadIdx.x;
    const int tx = tid & 15, ty = tid >> 4;
    const int m0 = blockIdx.y * TBM, n0 = blockIdx.x * TBN;
    const int mi = tid >> 2;
    const int pe = (tid & 3) << 2;

    float acc[4][4] = {};
    for (int k0 = 0; k0 < K; k0 += TBK) {
        const float4 av = *(const float4*)&Ab[(size_t)(m0 + mi) * lda + k0 + pe];
        As[pe + 0][mi] = av.x; As[pe + 1][mi] = av.y;
        As[pe + 2][mi] = av.z; As[pe + 3][mi] = av.w;
        const float4 bv = *(const float4*)&Bb[(size_t)(n0 + mi) * ldb + k0 + pe];
        Bs[pe + 0][mi] = bv.x; Bs[pe + 1][mi] = bv.y;
        Bs[pe + 2][mi] = bv.z; Bs[pe + 3][mi] = bv.w;
        __syncthreads();
#pragma unroll
        for (int p = 0; p < TBK; ++p) {
            const float4 a4 = *(const float4*)&As[p][ty << 2];
            const float4 b4 = *(const float4*)&Bs[p][tx << 2];
            const float ar[4] = {a4.x, a4.y, a4.z, a4.w};
            const float br[4] = {b4.x, b4.y, b4.z, b4.w};
#pragma unroll
            for (int i = 0; i < 4; ++i)
#pragma unroll
                for (int j = 0; j < 4; ++j) acc[i][j] += ar[i] * br[j];
        }
        __syncthreads();
    }
    float sr[4], sc[4];
#pragma unroll
    for (int i = 0; i < 4; ++i)
        sr[i] = sa ? sa[bz * L + m0 + (ty << 2) + i] : 1.f;
#pragma unroll
    for (int j = 0; j < 4; ++j)
        sc[j] = sb ? sb[bz * L + n0 + (tx << 2) + j] : 1.f;
#pragma unroll
    for (int i = 0; i < 4; ++i) {
        float4 o;
        o.x = acc[i][0] * sr[i] * sc[0];
        o.y = acc[i][1] * sr[i] * sc[1];
        o.z = acc[i][2] * sr[i] * sc[2];
        o.w = acc[i][3] * sr[i] * sc[3];
        *(float4*)&Cb[(size_t)(m0 + (ty << 2) + i) * ldc + n0 + (tx << 2)] = o;
    }
}

// ---------------- batched C = A · B (+ optional residual R) ----------------
__global__ __launch_bounds__(256)
void gemm_nn(const float* __restrict__ A, int lda, long long sA,
             const float* __restrict__ Bm, int ldb, long long sB,
             const float* __restrict__ R, int ldr, long long sR,
             float* __restrict__ Cc, int ldc, long long sC, int K)
{
    __shared__ float As[TBK][TBM];
    __shared__ float Bs[TBK][TBN];
    const int bz = blockIdx.z;
    const float* Ab = A + (size_t)bz * sA;
    const float* Bb = Bm + (size_t)bz * sB;
    float* Cb = Cc + (size_t)bz * sC;
    const int tid = threadIdx.x;
    const int tx = tid & 15, ty = tid >> 4;
    const int m0 = blockIdx.y * TBM, n0 = blockIdx.x * TBN;
    const int mi = tid >> 2;
    const int pe = (tid & 3) << 2;
    const int pi = tid >> 4;
    const int fi = (tid & 15) << 2;

    float acc[4][4] = {};
    for (int k0 = 0; k0 < K; k0 += TBK) {
        const float4 av = *(const float4*)&Ab[(size_t)(m0 + mi) * lda + k0 + pe];
        As[pe + 0][mi] = av.x; As[pe + 1][mi] = av.y;
        As[pe + 2][mi] = av.z; As[pe + 3][mi] = av.w;
        *(float4*)&Bs[pi][fi] = *(const float4*)&Bb[(size_t)(k0 + pi) * ldb + n0 + fi];
        __syncthreads();
#pragma unroll
        for (int p = 0; p < TBK; ++p) {
            const float4 a4 = *(const float4*)&As[p][ty << 2];
            const float4 b4 = *(const float4*)&Bs[p][tx << 2];
            const float ar[4] = {a4.x, a4.y, a4.z, a4.w};
            const float br[4] = {b4.x, b4.y, b4.z, b4.w};
#pragma unroll
            for (int i = 0; i < 4; ++i)
#pragma unroll
                for (int j = 0; j < 4; ++j) acc[i][j] += ar[i] * br[j];
        }
        __syncthreads();
    }
#pragma unroll
    for (int i = 0; i < 4; ++i) {
        const int m = m0 + (ty << 2) + i;
        const int n = n0 + (tx << 2);
        float4 o = make_float4(acc[i][0], acc[i][1], acc[i][2], acc[i][3]);
        if (R) {
            const float4 r = *(const float4*)&R[(size_t)bz * sR + (size_t)m * ldr + n];
            o.x += r.x; o.y += r.y; o.z += r.z; o.w += r.w;
        }
        *(float4*)&Cb[(size_t)m * ldc + n] = o;
    }
}

// ---------------- softmask2d rows (no scale): att = exp(S)*mask_j / (sum+eps) * mask_i
__global__ __launch_bounds__(256)
void softmask_rows(const float* __restrict__ S, const float* __restrict__ mask,
                   float* __restrict__ att)
{
    __shared__ float red[4];
    const int row = blockIdx.x;          // b*L + i
    const int b = row >> 9;
    const int i = row & (L - 1);
    const float* s_ = S + (size_t)row * L;
    float* a_ = att + (size_t)row * L;
    const int t = threadIdx.x;
    const int lane = t & 63, wid = t >> 6;
    const float e0 = expf(s_[t]) * mask[b * L + t];
    const float e1 = expf(s_[t + 256]) * mask[b * L + t + 256];
    float s = waveSum(e0 + e1);
    if (lane == 0) red[wid] = s;
    __syncthreads();
    const float tot = red[0] + red[1] + red[2] + red[3];
    const float sc = mask[b * L + i] / (tot + EPS);
    a_[t] = e0 * sc;
    a_[t + 256] = e1 * sc;
}

// ---------------- denominators for the transposed softmask (column sums of S)
__global__ __launch_bounds__(256)
void colsum_denomO(const float* __restrict__ S, const float* __restrict__ mask,
                   float* __restrict__ denomO)
{
    const int b = blockIdx.y;
    const int i = blockIdx.x * 256 + threadIdx.x;
    const float* Sb_ = S + (size_t)b * L * L;
    float s = 0.f;
    for (int j = 0; j < L; ++j) s += expf(Sb_[(size_t)j * L + i]) * mask[b * L + j];
    denomO[b * L + i] = s + EPS;
}

// ---------------- attO[b,i,j] = exp(S[b,j,i])*mask_j*mask_i/denomO[b,i] (tiled transpose)
__global__ __launch_bounds__(256)
void make_attO(const float* __restrict__ S, const float* __restrict__ mask,
               const float* __restrict__ denomO, float* __restrict__ attO)
{
    __shared__ float t[64][65];
    const int b = blockIdx.z;
    const int i0 = blockIdx.y * 64;   // output rows
    const int j0 = blockIdx.x * 64;   // output cols
    const float* Sb_ = S + (size_t)b * L * L;
    float* Ob = attO + (size_t)b * L * L;
    const int tx = threadIdx.x & 15, ty = threadIdx.x >> 4;
#pragma unroll
    for (int rr = 0; rr < 4; ++rr) {
        const int r = rr * 16 + ty;
        const float4 v = *(const float4*)&Sb_[(size_t)(j0 + r) * L + i0 + tx * 4];
        t[r][tx * 4 + 0] = v.x; t[r][tx * 4 + 1] = v.y;
        t[r][tx * 4 + 2] = v.z; t[r][tx * 4 + 3] = v.w;
    }
    __syncthreads();
#pragma unroll
    for (int rr = 0; rr < 4; ++rr) {
        const int r = rr * 16 + ty;              // output row local
        const int i = i0 + r;
        const int c = tx * 4;                    // output col local
        const float mi_d = mask[b * L + i] / denomO[b * L + i];
        float4 o;
        o.x = expf(t[c + 0][r]) * mask[b * L + j0 + c + 0] * mi_d;
        o.y = expf(t[c + 1][r]) * mask[b * L + j0 + c + 1] * mi_d;
        o.z = expf(t[c + 2][r]) * mask[b * L + j0 + c + 2] * mi_d;
        o.w = expf(t[c + 3][r]) * mask[b * L + j0 + c + 3] * mi_d;
        *(float4*)&Ob[(size_t)i * L + j0 + c] = o;
    }
}

// ---------------- pred = In @ Wd + bd (C=3); optional opinion confidence ----------------
__global__ __launch_bounds__(256)
void pred3(const float* __restrict__ In, int ldi, int K,
           const float* __restrict__ Wd, const float* __restrict__ bd,
           float* __restrict__ pred, float* __restrict__ conf)
{
    __shared__ float sW[3 * 1024];
    for (int t = threadIdx.x; t < K * 3; t += 256) sW[t] = Wd[t];
    __syncthreads();
    const int wid = threadIdx.x >> 6, lane = threadIdx.x & 63;
    const int m = blockIdx.x * 4 + wid;
    const float* row = In + (size_t)m * ldi;
    float a0 = 0.f, a1 = 0.f, a2 = 0.f;
    for (int h = lane; h < K; h += 64) {
        const float v = row[h];
        a0 += v * sW[h * 3 + 0];
        a1 += v * sW[h * 3 + 1];
        a2 += v * sW[h * 3 + 2];
    }
    a0 = waveSum(a0); a1 = waveSum(a1); a2 = waveSum(a2);
    if (lane == 0) {
        a0 += bd[0]; a1 += bd[1]; a2 += bd[2];
        pred[(size_t)m * 3 + 0] = a0;
        pred[(size_t)m * 3 + 1] = a1;
        pred[(size_t)m * 3 + 2] = a2;
        if (conf) {
            const float mx = fmaxf(a0, fmaxf(a1, a2));
            const float z0 = expf(a0 - mx), z1 = expf(a1 - mx), z2 = expf(a2 - mx);
            const float p0 = z0 / (z0 + z1 + z2);
            conf[m] = fmaxf(0.f, 1.f - 2.f * p0);
        }
    }
}

// ---------------- column sums of position_att ----------------
__global__ __launch_bounds__(256)
void colsum_pos(const float* __restrict__ P, float* __restrict__ Pb)
{
    const int b = blockIdx.y;
    const int k = blockIdx.x * 256 + threadIdx.x;
    const float* p = P + (size_t)b * L * L;
    float s = 0.f;
    for (int j = 0; j < L; ++j) s += p[(size_t)j * L + k];
    Pb[b * L + k] = s;
}

// ---------------- row sums of mask ----------------
__global__ __launch_bounds__(256)
void rowsum_mask(const float* __restrict__ mask, float* __restrict__ Sb)
{
    __shared__ float red[4];
    const int b = blockIdx.x;
    float s = 0.f;
    for (int j = threadIdx.x; j < L; j += 256) s += mask[b * L + j];
    s = waveSum(s);
    const int lane = threadIdx.x & 63, wid = threadIdx.x >> 6;
    if (lane == 0) red[wid] = s;
    __syncthreads();
    if (threadIdx.x == 0) Sb[b] = red[0] + red[1] + red[2] + red[3];
}

// ---------------- combined = softmask_scaled(WSC2) + attA + conf*Sb*Pb (in place) ----
__global__ __launch_bounds__(256)
void combined_att(float* __restrict__ WSC2, const float* __restrict__ attA,
                  const float* __restrict__ mask, const float* __restrict__ conf,
                  const float* __restrict__ Sb, const float* __restrict__ Pb)
{
    __shared__ float red[4];
    const int row = blockIdx.x;          // b*L + i
    const int b = row >> 9;
    const int i = row & (L - 1);
    float* x = WSC2 + (size_t)row * L;
    const float* aA = attA + (size_t)row * L;
    const int t = threadIdx.x;
    const int lane = t & 63, wid = t >> 6;
    const float x0 = x[t], x1 = x[t + 256];
    float v = waveMax(fmaxf(x0, x1));
    if (lane == 0) red[wid] = v;
    __syncthreads();
    const float mx = fmaxf(fmaxf(red[0], red[1]), fmaxf(red[2], red[3]));
    const float e0 = expf(x0 - mx) * mask[b * L + t];
    const float e1 = expf(x1 - mx) * mask[b * L + t + 256];
    float s = waveSum(e0 + e1);
    __syncthreads();
    if (lane == 0) red[wid] = s;
    __syncthreads();
    const float tot = red[0] + red[1] + red[2] + red[3];
    const float sc = mask[b * L + i] / (tot + EPS);
    const float add = conf[row] * Sb[b];
    x[t]       = e0 * sc + aA[t]       + add * Pb[b * L + t];
    x[t + 256] = e1 * sc + aA[t + 256] + add * Pb[b * L + t + 256];
}

} // namespace

extern "C" void kernel_launch(void* const* d_in, const int* in_sizes, int n_in,
                              void* d_out, int out_size, void* d_ws, size_t ws_size,
                              hipStream_t stream)
{
    const float* aspect_in  = (const float*)d_in[0];
    const float* opinion_in = (const float*)d_in[1];
    const float* context_in = (const float*)d_in[2];
    const float* context_q  = (const float*)d_in[3];
    const float* mask       = (const float*)d_in[4];
    const float* pos_att    = (const float*)d_in[5];
    const float* Wa  = (const float*)d_in[6];  const float* ba  = (const float*)d_in[7];
    const float* Wo  = (const float*)d_in[8];  const float* bo  = (const float*)d_in[9];
    const float* Wc  = (const float*)d_in[10]; const float* bc  = (const float*)d_in[11];
    const float* Wda = (const float*)d_in[12]; const float* bda = (const float*)d_in[13];
    const float* Wdo = (const float*)d_in[14]; const float* bdo = (const float*)d_in[15];
    const float* Wds = (const float*)d_in[16]; const float* bds = (const float*)d_in[17];

    float* out = (float*)d_out;
    const size_t BL = (size_t)NB * L;
    float* aspect_pred    = out;
    float* opinion_pred   = out + BL * 3;
    float* sentiment_pred = out + BL * 6;
    float* aspect_int     = out + BL * 9;                 // [BL, 1024]
    float* opinion_int    = aspect_int + BL * 2 * F;      // [BL, 1024]
    float* context_int    = opinion_int + BL * 2 * F;     // [BL, 768]
    float* context_conv   = context_int + BL * E;         // [BL, 768]

    float* ws = (float*)d_ws;
    const long long LL = (long long)L * L;
    const size_t BLL = (size_t)NB * L * L;
    float* buf1   = ws;               // S -> later WSC2/combined att
    float* buf2   = buf1 + BLL;       // attA
    float* buf3   = buf2 + BLL;       // attO -> later WSC1
    float* inv_a  = buf3 + BLL;
    float* inv_o  = inv_a + BL;
    float* inv_c  = inv_o + BL;
    float* denomO = inv_c + BL;
    float* conf   = denomO + BL;
    float* Pb     = conf + BL;
    float* Sbv    = Pb + BL;

    const long long sAO = (long long)L * 2 * F;   // batch stride of interact-resident convs
    const long long sE  = (long long)L * E;

    // 1) conv1d + relu (aspect/opinion write into first half of their interact slots)
    conv_gemm_relu<<<dim3(F / TBN, (NB * L) / TBM), 256, 0, stream>>>(aspect_in, Wa, ba, aspect_int, F, 2 * F);
    conv_gemm_relu<<<dim3(F / TBN, (NB * L) / TBM), 256, 0, stream>>>(opinion_in, Wo, bo, opinion_int, F, 2 * F);
    conv_gemm_relu<<<dim3(E / TBN, (NB * L) / TBM), 256, 0, stream>>>(context_in, Wc, bc, context_conv, E, E);

    // 2) inverse L2 norms (normalization folded into GEMM epilogues)
    inv_l2norm<<<NB * L, 256, 0, stream>>>(aspect_int, F, 2 * F, inv_a);
    inv_l2norm<<<NB * L, 256, 0, stream>>>(opinion_int, F, 2 * F, inv_o);
    inv_l2norm<<<NB * L, 256, 0, stream>>>(context_conv, E, E, inv_c);

    // 3) S = (a_n . o_n^T)  -> buf1   (opinion_see_aspect = S^T, computed once)
    gemm_nt<<<dim3(L / TBN, L / TBM, NB), 256, 0, stream>>>(
        aspect_int, 2 * F, sAO, opinion_int, 2 * F, sAO, buf1, L, LL, F, inv_a, inv_o);

    // 4) attA = softmask(S) -> buf2 ; attO = softmask(S^T) -> buf3
    softmask_rows<<<NB * L, 256, 0, stream>>>(buf1, mask, buf2);
    colsum_denomO<<<dim3(L / 256, NB), 256, 0, stream>>>(buf1, mask, denomO);
    make_attO<<<dim3(L / 64, L / 64, NB), 256, 0, stream>>>(buf1, mask, denomO, buf3);

    // 5) weigh GEMMs -> second halves of interact slots
    gemm_nn<<<dim3(F / TBN, L / TBM, NB), 256, 0, stream>>>(
        buf2, L, LL, opinion_int, 2 * F, sAO, nullptr, 0, 0, aspect_int + F, 2 * F, sAO, L);
    gemm_nn<<<dim3(F / TBN, L / TBM, NB), 256, 0, stream>>>(
        buf3, L, LL, aspect_int, 2 * F, sAO, nullptr, 0, 0, opinion_int + F, 2 * F, sAO, L);

    // 6) aspect/opinion predictions (+ opinion confidence)
    pred3<<<(NB * L) / 4, 256, 0, stream>>>(aspect_int, 2 * F, 2 * F, Wda, bda, aspect_pred, nullptr);
    pred3<<<(NB * L) / 4, 256, 0, stream>>>(opinion_int, 2 * F, 2 * F, Wdo, bdo, opinion_pred, conf);

    // 7) rank-1 collapse of opinion_propagated: conf[b,i] * Sb[b] * colsum(pos_att)[b,k]
    colsum_pos<<<dim3(L / 256, NB), 256, 0, stream>>>(pos_att, Pb);
    rowsum_mask<<<NB, 256, 0, stream>>>(mask, Sbv);

    // 8) WSC1 = cq . c_n^T -> buf3
    gemm_nt<<<dim3(L / TBN, L / TBM, NB), 256, 0, stream>>>(
        context_q, E, sE, context_conv, E, sE, buf3, L, LL, E, nullptr, inv_c);

    // 9) WSC2 = WSC1 @ pos_att -> buf1
    gemm_nn<<<dim3(L / TBN, L / TBM, NB), 256, 0, stream>>>(
        buf3, L, LL, pos_att, L, LL, nullptr, 0, 0, buf1, L, LL, L);

    // 10) combined attention (in place, buf1)
    combined_att<<<NB * L, 256, 0, stream>>>(buf1, buf2, mask, conf, Sbv, Pb);

    // 11) context_interact = cq + combined @ context_conv
    gemm_nn<<<dim3(E / TBN, L / TBM, NB), 256, 0, stream>>>(
        buf1, L, LL, context_conv, E, sE, context_q, E, sE, context_int, E, sE, L);

    // 12) sentiment prediction
    pred3<<<(NB * L) / 4, 256, 0, stream>>>(context_int, E, E, Wds, bds, sentiment_pred, nullptr);
}

// Round 2
// 1999.928 us; speedup vs baseline: 1.5906x; 1.5906x over previous
//
#include <hip/hip_runtime.h>
#include <math.h>

namespace {

constexpr int NB = 32;     // batch
constexpr int L  = 512;
constexpr int E  = 768;
constexpr int F  = 512;
constexpr float EPS = 1e-7f;

constexpr int TBM = 64, TBN = 64, TBK = 16;

typedef __attribute__((ext_vector_type(8))) short bfrag8;   // 8 bf16 (4 VGPRs)
typedef __attribute__((ext_vector_type(4))) float f32x4;    // MFMA accumulator

__device__ __forceinline__ float waveSum(float v) {
#pragma unroll
    for (int off = 32; off > 0; off >>= 1) v += __shfl_down(v, off, 64);
    return v;
}
__device__ __forceinline__ float waveMax(float v) {
#pragma unroll
    for (int off = 32; off > 0; off >>= 1) v = fmaxf(v, __shfl_down(v, off, 64));
    return v;
}

// split 8 fp32 -> 8 bf16 hi (packed uint4) + 8 bf16 lo (packed uint4).
// hi = truncate-to-bf16; lo = truncate-to-bf16(f - hi). Dropped lo*lo term
// plus truncation residual ~= 3*2^-16 relative — far inside fp32-ref tolerance.
__device__ __forceinline__ void split8(const float* f, uint4& hi, uint4& lo) {
    unsigned h[8], l[8];
#pragma unroll
    for (int i = 0; i < 8; ++i) {
        const unsigned x = __float_as_uint(f[i]);
        const unsigned hb = x & 0xffff0000u;
        h[i] = hb;
        const float r = f[i] - __uint_as_float(hb);
        l[i] = __float_as_uint(r) & 0xffff0000u;
    }
    hi = make_uint4((h[0] >> 16) | h[1], (h[2] >> 16) | h[3],
                    (h[4] >> 16) | h[5], (h[6] >> 16) | h[7]);
    lo = make_uint4((l[0] >> 16) | l[1], (l[2] >> 16) | l[3],
                    (l[4] >> 16) | l[5], (l[6] >> 16) | l[7]);
}

// ---------------- conv1d (K=3, SAME) as split-bf16 MFMA GEMM + bias + relu ------
// Out[m,f] = relu(bias[f] + sum_{kk,e} X[b, l+kk-1, e] * W[kk,e,f]),  m = b*L+l
// 128x128 tile, BK=32, 4 waves (2x2 of 64x64), mfma_f32_16x16x32_bf16.
// LDS tiles [row][32] bf16 hi/lo, 16B chunks XOR-swizzled by (row&3) so both the
// staging writes and the per-wave ds_read_b128 frag reads spread evenly over banks.
__global__ __launch_bounds__(256, 2)
void conv_mfma(const float* __restrict__ X,    // [NB,L,E]
               const float* __restrict__ W,    // [3,E,Cout]
               const float* __restrict__ bias, // [Cout]
               float* __restrict__ Out,        // row stride ldo
               int Cout, int ldo)
{
    __shared__ __align__(16) short Ah[128 * 32];
    __shared__ __align__(16) short Al[128 * 32];
    __shared__ __align__(16) short Bh[128 * 32];
    __shared__ __align__(16) short Bl[128 * 32];

    const int t = threadIdx.x;
    const int lane = t & 63;
    const int wid = t >> 6;
    const int wm = (wid & 2) * 32;     // wave row offset: 0 or 64
    const int wn = (wid & 1) * 64;     // wave col offset: 0 or 64
    const int m0 = blockIdx.y * 128;
    const int n0 = blockIdx.x * 128;

    // staging roles
    const int ar = t >> 1;             // A row 0..127
    const int ah_half = t & 1;         // which 16-float half of the 32-wide row
    const int bn = t & 127;            // B LDS row (= output col)
    const int bk_half = t >> 7;        // which 16 of the 32 k values

    // frag-read lane geometry
    const int rl = lane & 15;
    const int chl = ((lane >> 4) ^ (lane & 3)) << 3;   // swizzled chunk offset (shorts)

    f32x4 acc[4][4] = {};

    for (int kk = 0; kk < 3; ++kk) {
        const int m = m0 + ar;
        const int bb = m >> 9;
        const int ll = (m & (L - 1)) + kk - 1;
        const bool valid = (ll >= 0) && (ll < L);
        const float* arow = X + ((size_t)bb * L + (valid ? ll : 0)) * E + ah_half * 16;

        for (int e0 = 0; e0 < E; e0 += 32) {
            // ---- global loads to regs ----
            float av[16];
            const float4* ap = (const float4*)(arow + e0);
#pragma unroll
            for (int q = 0; q < 4; ++q) {
                float4 v = valid ? ap[q] : make_float4(0.f, 0.f, 0.f, 0.f);
                av[q * 4 + 0] = v.x; av[q * 4 + 1] = v.y;
                av[q * 4 + 2] = v.z; av[q * 4 + 3] = v.w;
            }
            float bv[16];
            const float* bp = W + ((size_t)(kk * E + e0 + bk_half * 16)) * Cout + n0 + bn;
#pragma unroll
            for (int i = 0; i < 16; ++i) bv[i] = bp[(size_t)i * Cout];

            // ---- convert + stage ----
            uint4 h0, l0, h1, l1;
            split8(av + 0, h0, l0);
            split8(av + 8, h1, l1);
            uint4 g0, m0v, g1, m1v;
            split8(bv + 0, g0, m0v);
            split8(bv + 8, g1, m1v);

            __syncthreads();   // previous chunk's frag reads complete
            {
                const int c0 = ah_half * 2;
                const int s0 = ((c0 ^ (ar & 3)) << 3);
                const int s1 = (((c0 + 1) ^ (ar & 3)) << 3);
                *(uint4*)&Ah[ar * 32 + s0] = h0;
                *(uint4*)&Al[ar * 32 + s0] = l0;
                *(uint4*)&Ah[ar * 32 + s1] = h1;
                *(uint4*)&Al[ar * 32 + s1] = l1;
                const int d0 = bk_half * 2;
                const int u0 = ((d0 ^ (bn & 3)) << 3);
                const int u1 = (((d0 + 1) ^ (bn & 3)) << 3);
                *(uint4*)&Bh[bn * 32 + u0] = g0;
                *(uint4*)&Bl[bn * 32 + u0] = m0v;
                *(uint4*)&Bh[bn * 32 + u1] = g1;
                *(uint4*)&Bl[bn * 32 + u1] = m1v;
            }
            __syncthreads();   // tiles ready

            // ---- frag reads + MFMA ----
            bfrag8 fah[4], fal[4], fbh[4], fbl[4];
#pragma unroll
            for (int i = 0; i < 4; ++i) {
                const int rowa = (wm + i * 16 + rl) * 32 + chl;
                fah[i] = *(const bfrag8*)&Ah[rowa];
                fal[i] = *(const bfrag8*)&Al[rowa];
                const int rowb = (wn + i * 16 + rl) * 32 + chl;
                fbh[i] = *(const bfrag8*)&Bh[rowb];
                fbl[i] = *(const bfrag8*)&Bl[rowb];
            }
#pragma unroll
            for (int i = 0; i < 4; ++i)
#pragma unroll
                for (int j = 0; j < 4; ++j) {
                    acc[i][j] = __builtin_amdgcn_mfma_f32_16x16x32_bf16(
                        fah[i], fbh[j], acc[i][j], 0, 0, 0);
                    acc[i][j] = __builtin_amdgcn_mfma_f32_16x16x32_bf16(
                        fal[i], fbh[j], acc[i][j], 0, 0, 0);
                    acc[i][j] = __builtin_amdgcn_mfma_f32_16x16x32_bf16(
                        fah[i], fbl[j], acc[i][j], 0, 0, 0);
                }
        }
    }

    // ---- epilogue: bias + relu ----
    const int rbase = m0 + wm + (lane >> 4) * 4;
    const int cbase = n0 + wn + (lane & 15);
#pragma unroll
    for (int j = 0; j < 4; ++j) {
        const float bj = bias[cbase + j * 16];
#pragma unroll
        for (int i = 0; i < 4; ++i) {
#pragma unroll
            for (int g = 0; g < 4; ++g) {
                const int row = rbase + i * 16 + g;
                Out[(size_t)row * ldo + cbase + j * 16] = fmaxf(acc[i][j][g] + bj, 0.f);
            }
        }
    }
}

// ---------------- inverse L2 norm of each row ----------------
__global__ __launch_bounds__(256)
void inv_l2norm(const float* __restrict__ Xp, int len, int ld, float* __restrict__ inv)
{
    __shared__ float red[4];
    const int m = blockIdx.x;
    const float* row = Xp + (size_t)m * ld;
    float s = 0.f;
    for (int h = threadIdx.x; h < len; h += 256) { const float v = row[h]; s += v * v; }
    s = waveSum(s);
    const int lane = threadIdx.x & 63, wid = threadIdx.x >> 6;
    if (lane == 0) red[wid] = s;
    __syncthreads();
    if (threadIdx.x == 0)
        inv[m] = 1.0f / sqrtf(fmaxf(red[0] + red[1] + red[2] + red[3], 1e-12f));
}

// ---------------- batched C = (A · B^T) * sa[i] * sb[j] ----------------
__global__ __launch_bounds__(256)
void gemm_nt(const float* __restrict__ A, int lda, long long sA,
             const float* __restrict__ Bm, int ldb, long long sB,
             float* __restrict__ Cc, int ldc, long long sC, int K,
             const float* __restrict__ sa, const float* __restrict__ sb)
{
    __shared__ float As[TBK][TBM];
    __shared__ float Bs[TBK][TBN];
    const int bz = blockIdx.z;
    const float* Ab = A + (size_t)bz * sA;
    const float* Bb = Bm + (size_t)bz * sB;
    float* Cb = Cc + (size_t)bz * sC;
    const int tid = threadIdx.x;
    const int tx = tid & 15, ty = tid >> 4;
    const int m0 = blockIdx.y * TBM, n0 = blockIdx.x * TBN;
    const int mi = tid >> 2;
    const int pe = (tid & 3) << 2;

    float acc[4][4] = {};
    for (int k0 = 0; k0 < K; k0 += TBK) {
        const float4 av = *(const float4*)&Ab[(size_t)(m0 + mi) * lda + k0 + pe];
        As[pe + 0][mi] = av.x; As[pe + 1][mi] = av.y;
        As[pe + 2][mi] = av.z; As[pe + 3][mi] = av.w;
        const float4 bv = *(const float4*)&Bb[(size_t)(n0 + mi) * ldb + k0 + pe];
        Bs[pe + 0][mi] = bv.x; Bs[pe + 1][mi] = bv.y;
        Bs[pe + 2][mi] = bv.z; Bs[pe + 3][mi] = bv.w;
        __syncthreads();
#pragma unroll
        for (int p = 0; p < TBK; ++p) {
            const float4 a4 = *(const float4*)&As[p][ty << 2];
            const float4 b4 = *(const float4*)&Bs[p][tx << 2];
            const float ar[4] = {a4.x, a4.y, a4.z, a4.w};
            const float br[4] = {b4.x, b4.y, b4.z, b4.w};
#pragma unroll
            for (int i = 0; i < 4; ++i)
#pragma unroll
                for (int j = 0; j < 4; ++j) acc[i][j] += ar[i] * br[j];
        }
        __syncthreads();
    }
    float sr[4], sc[4];
#pragma unroll
    for (int i = 0; i < 4; ++i)
        sr[i] = sa ? sa[bz * L + m0 + (ty << 2) + i] : 1.f;
#pragma unroll
    for (int j = 0; j < 4; ++j)
        sc[j] = sb ? sb[bz * L + n0 + (tx << 2) + j] : 1.f;
#pragma unroll
    for (int i = 0; i < 4; ++i) {
        float4 o;
        o.x = acc[i][0] * sr[i] * sc[0];
        o.y = acc[i][1] * sr[i] * sc[1];
        o.z = acc[i][2] * sr[i] * sc[2];
        o.w = acc[i][3] * sr[i] * sc[3];
        *(float4*)&Cb[(size_t)(m0 + (ty << 2) + i) * ldc + n0 + (tx << 2)] = o;
    }
}

// ---------------- batched C = A · B (+ optional residual R) ----------------
__global__ __launch_bounds__(256)
void gemm_nn(const float* __restrict__ A, int lda, long long sA,
             const float* __restrict__ Bm, int ldb, long long sB,
             const float* __restrict__ R, int ldr, long long sR,
             float* __restrict__ Cc, int ldc, long long sC, int K)
{
    __shared__ float As[TBK][TBM];
    __shared__ float Bs[TBK][TBN];
    const int bz = blockIdx.z;
    const float* Ab = A + (size_t)bz * sA;
    const float* Bb = Bm + (size_t)bz * sB;
    float* Cb = Cc + (size_t)bz * sC;
    const int tid = threadIdx.x;
    const int tx = tid & 15, ty = tid >> 4;
    const int m0 = blockIdx.y * TBM, n0 = blockIdx.x * TBN;
    const int mi = tid >> 2;
    const int pe = (tid & 3) << 2;
    const int pi = tid >> 4;
    const int fi = (tid & 15) << 2;

    float acc[4][4] = {};
    for (int k0 = 0; k0 < K; k0 += TBK) {
        const float4 av = *(const float4*)&Ab[(size_t)(m0 + mi) * lda + k0 + pe];
        As[pe + 0][mi] = av.x; As[pe + 1][mi] = av.y;
        As[pe + 2][mi] = av.z; As[pe + 3][mi] = av.w;
        *(float4*)&Bs[pi][fi] = *(const float4*)&Bb[(size_t)(k0 + pi) * ldb + n0 + fi];
        __syncthreads();
#pragma unroll
        for (int p = 0; p < TBK; ++p) {
            const float4 a4 = *(const float4*)&As[p][ty << 2];
            const float4 b4 = *(const float4*)&Bs[p][tx << 2];
            const float ar[4] = {a4.x, a4.y, a4.z, a4.w};
            const float br[4] = {b4.x, b4.y, b4.z, b4.w};
#pragma unroll
            for (int i = 0; i < 4; ++i)
#pragma unroll
                for (int j = 0; j < 4; ++j) acc[i][j] += ar[i] * br[j];
        }
        __syncthreads();
    }
#pragma unroll
    for (int i = 0; i < 4; ++i) {
        const int m = m0 + (ty << 2) + i;
        const int n = n0 + (tx << 2);
        float4 o = make_float4(acc[i][0], acc[i][1], acc[i][2], acc[i][3]);
        if (R) {
            const float4 r = *(const float4*)&R[(size_t)bz * sR + (size_t)m * ldr + n];
            o.x += r.x; o.y += r.y; o.z += r.z; o.w += r.w;
        }
        *(float4*)&Cb[(size_t)m * ldc + n] = o;
    }
}

// ---------------- softmask2d rows (no scale) ----------------
__global__ __launch_bounds__(256)
void softmask_rows(const float* __restrict__ S, const float* __restrict__ mask,
                   float* __restrict__ att)
{
    __shared__ float red[4];
    const int row = blockIdx.x;          // b*L + i
    const int b = row >> 9;
    const int i = row & (L - 1);
    const float* s_ = S + (size_t)row * L;
    float* a_ = att + (size_t)row * L;
    const int t = threadIdx.x;
    const int lane = t & 63, wid = t >> 6;
    const float e0 = expf(s_[t]) * mask[b * L + t];
    const float e1 = expf(s_[t + 256]) * mask[b * L + t + 256];
    float s = waveSum(e0 + e1);
    if (lane == 0) red[wid] = s;
    __syncthreads();
    const float tot = red[0] + red[1] + red[2] + red[3];
    const float sc = mask[b * L + i] / (tot + EPS);
    a_[t] = e0 * sc;
    a_[t + 256] = e1 * sc;
}

// ---------------- denominators for the transposed softmask ----------------
__global__ __launch_bounds__(256)
void colsum_denomO(const float* __restrict__ S, const float* __restrict__ mask,
                   float* __restrict__ denomO)
{
    const int b = blockIdx.y;
    const int i = blockIdx.x * 256 + threadIdx.x;
    const float* Sb_ = S + (size_t)b * L * L;
    float s = 0.f;
    for (int j = 0; j < L; ++j) s += expf(Sb_[(size_t)j * L + i]) * mask[b * L + j];
    denomO[b * L + i] = s + EPS;
}

// ---------------- attO[b,i,j] = exp(S[b,j,i])*mask_j*mask_i/denomO[b,i] ------
__global__ __launch_bounds__(256)
void make_attO(const float* __restrict__ S, const float* __restrict__ mask,
               const float* __restrict__ denomO, float* __restrict__ attO)
{
    __shared__ float t[64][65];
    const int b = blockIdx.z;
    const int i0 = blockIdx.y * 64;   // output rows
    const int j0 = blockIdx.x * 64;   // output cols
    const float* Sb_ = S + (size_t)b * L * L;
    float* Ob = attO + (size_t)b * L * L;
    const int tx = threadIdx.x & 15, ty = threadIdx.x >> 4;
#pragma unroll
    for (int rr = 0; rr < 4; ++rr) {
        const int r = rr * 16 + ty;
        const float4 v = *(const float4*)&Sb_[(size_t)(j0 + r) * L + i0 + tx * 4];
        t[r][tx * 4 + 0] = v.x; t[r][tx * 4 + 1] = v.y;
        t[r][tx * 4 + 2] = v.z; t[r][tx * 4 + 3] = v.w;
    }
    __syncthreads();
#pragma unroll
    for (int rr = 0; rr < 4; ++rr) {
        const int r = rr * 16 + ty;
        const int i = i0 + r;
        const int c = tx * 4;
        const float mi_d = mask[b * L + i] / denomO[b * L + i];
        float4 o;
        o.x = expf(t[c + 0][r]) * mask[b * L + j0 + c + 0] * mi_d;
        o.y = expf(t[c + 1][r]) * mask[b * L + j0 + c + 1] * mi_d;
        o.z = expf(t[c + 2][r]) * mask[b * L + j0 + c + 2] * mi_d;
        o.w = expf(t[c + 3][r]) * mask[b * L + j0 + c + 3] * mi_d;
        *(float4*)&Ob[(size_t)i * L + j0 + c] = o;
    }
}

// ---------------- pred = In @ Wd + bd (C=3); optional opinion confidence ------
__global__ __launch_bounds__(256)
void pred3(const float* __restrict__ In, int ldi, int K,
           const float* __restrict__ Wd, const float* __restrict__ bd,
           float* __restrict__ pred, float* __restrict__ conf)
{
    __shared__ float sW[3 * 1024];
    for (int t = threadIdx.x; t < K * 3; t += 256) sW[t] = Wd[t];
    __syncthreads();
    const int wid = threadIdx.x >> 6, lane = threadIdx.x & 63;
    const int m = blockIdx.x * 4 + wid;
    const float* row = In + (size_t)m * ldi;
    float a0 = 0.f, a1 = 0.f, a2 = 0.f;
    for (int h = lane; h < K; h += 64) {
        const float v = row[h];
        a0 += v * sW[h * 3 + 0];
        a1 += v * sW[h * 3 + 1];
        a2 += v * sW[h * 3 + 2];
    }
    a0 = waveSum(a0); a1 = waveSum(a1); a2 = waveSum(a2);
    if (lane == 0) {
        a0 += bd[0]; a1 += bd[1]; a2 += bd[2];
        pred[(size_t)m * 3 + 0] = a0;
        pred[(size_t)m * 3 + 1] = a1;
        pred[(size_t)m * 3 + 2] = a2;
        if (conf) {
            const float mx = fmaxf(a0, fmaxf(a1, a2));
            const float z0 = expf(a0 - mx), z1 = expf(a1 - mx), z2 = expf(a2 - mx);
            const float p0 = z0 / (z0 + z1 + z2);
            conf[m] = fmaxf(0.f, 1.f - 2.f * p0);
        }
    }
}

// ---------------- column sums of position_att ----------------
__global__ __launch_bounds__(256)
void colsum_pos(const float* __restrict__ P, float* __restrict__ Pb)
{
    const int b = blockIdx.y;
    const int k = blockIdx.x * 256 + threadIdx.x;
    const float* p = P + (size_t)b * L * L;
    float s = 0.f;
    for (int j = 0; j < L; ++j) s += p[(size_t)j * L + k];
    Pb[b * L + k] = s;
}

// ---------------- row sums of mask ----------------
__global__ __launch_bounds__(256)
void rowsum_mask(const float* __restrict__ mask, float* __restrict__ Sb)
{
    __shared__ float red[4];
    const int b = blockIdx.x;
    float s = 0.f;
    for (int j = threadIdx.x; j < L; j += 256) s += mask[b * L + j];
    s = waveSum(s);
    const int lane = threadIdx.x & 63, wid = threadIdx.x >> 6;
    if (lane == 0) red[wid] = s;
    __syncthreads();
    if (threadIdx.x == 0) Sb[b] = red[0] + red[1] + red[2] + red[3];
}

// ---------------- combined = softmask_scaled(WSC2) + attA + conf*Sb*Pb --------
__global__ __launch_bounds__(256)
void combined_att(float* __restrict__ WSC2, const float* __restrict__ attA,
                  const float* __restrict__ mask, const float* __restrict__ conf,
                  const float* __restrict__ Sb, const float* __restrict__ Pb)
{
    __shared__ float red[4];
    const int row = blockIdx.x;          // b*L + i
    const int b = row >> 9;
    const int i = row & (L - 1);
    float* x = WSC2 + (size_t)row * L;
    const float* aA = attA + (size_t)row * L;
    const int t = threadIdx.x;
    const int lane = t & 63, wid = t >> 6;
    const float x0 = x[t], x1 = x[t + 256];
    float v = waveMax(fmaxf(x0, x1));
    if (lane == 0) red[wid] = v;
    __syncthreads();
    const float mx = fmaxf(fmaxf(red[0], red[1]), fmaxf(red[2], red[3]));
    const float e0 = expf(x0 - mx) * mask[b * L + t];
    const float e1 = expf(x1 - mx) * mask[b * L + t + 256];
    float s = waveSum(e0 + e1);
    __syncthreads();
    if (lane == 0) red[wid] = s;
    __syncthreads();
    const float tot = red[0] + red[1] + red[2] + red[3];
    const float sc = mask[b * L + i] / (tot + EPS);
    const float add = conf[row] * Sb[b];
    x[t]       = e0 * sc + aA[t]       + add * Pb[b * L + t];
    x[t + 256] = e1 * sc + aA[t + 256] + add * Pb[b * L + t + 256];
}

} // namespace

extern "C" void kernel_launch(void* const* d_in, const int* in_sizes, int n_in,
                              void* d_out, int out_size, void* d_ws, size_t ws_size,
                              hipStream_t stream)
{
    const float* aspect_in  = (const float*)d_in[0];
    const float* opinion_in = (const float*)d_in[1];
    const float* context_in = (const float*)d_in[2];
    const float* context_q  = (const float*)d_in[3];
    const float* mask       = (const float*)d_in[4];
    const float* pos_att    = (const float*)d_in[5];
    const float* Wa  = (const float*)d_in[6];  const float* ba  = (const float*)d_in[7];
    const float* Wo  = (const float*)d_in[8];  const float* bo  = (const float*)d_in[9];
    const float* Wc  = (const float*)d_in[10]; const float* bc  = (const float*)d_in[11];
    const float* Wda = (const float*)d_in[12]; const float* bda = (const float*)d_in[13];
    const float* Wdo = (const float*)d_in[14]; const float* bdo = (const float*)d_in[15];
    const float* Wds = (const float*)d_in[16]; const float* bds = (const float*)d_in[17];

    float* out = (float*)d_out;
    const size_t BL = (size_t)NB * L;
    float* aspect_pred    = out;
    float* opinion_pred   = out + BL * 3;
    float* sentiment_pred = out + BL * 6;
    float* aspect_int     = out + BL * 9;                 // [BL, 1024]
    float* opinion_int    = aspect_int + BL * 2 * F;      // [BL, 1024]
    float* context_int    = opinion_int + BL * 2 * F;     // [BL, 768]
    float* context_conv   = context_int + BL * E;         // [BL, 768]

    float* ws = (float*)d_ws;
    const long long LL = (long long)L * L;
    const size_t BLL = (size_t)NB * L * L;
    float* buf1   = ws;               // S -> later WSC2/combined att
    float* buf2   = buf1 + BLL;       // attA
    float* buf3   = buf2 + BLL;       // attO -> later WSC1
    float* inv_a  = buf3 + BLL;
    float* inv_o  = inv_a + BL;
    float* inv_c  = inv_o + BL;
    float* denomO = inv_c + BL;
    float* conf   = denomO + BL;
    float* Pb     = conf + BL;
    float* Sbv    = Pb + BL;

    const long long sAO = (long long)L * 2 * F;   // batch stride of interact-resident convs
    const long long sE  = (long long)L * E;

    // 1) conv1d + relu via split-bf16 MFMA (fp32-accurate 3-product emulation)
    conv_mfma<<<dim3(F / 128, (NB * L) / 128), 256, 0, stream>>>(aspect_in, Wa, ba, aspect_int, F, 2 * F);
    conv_mfma<<<dim3(F / 128, (NB * L) / 128), 256, 0, stream>>>(opinion_in, Wo, bo, opinion_int, F, 2 * F);
    conv_mfma<<<dim3(E / 128, (NB * L) / 128), 256, 0, stream>>>(context_in, Wc, bc, context_conv, E, E);

    // 2) inverse L2 norms (normalization folded into GEMM epilogues)
    inv_l2norm<<<NB * L, 256, 0, stream>>>(aspect_int, F, 2 * F, inv_a);
    inv_l2norm<<<NB * L, 256, 0, stream>>>(opinion_int, F, 2 * F, inv_o);
    inv_l2norm<<<NB * L, 256, 0, stream>>>(context_conv, E, E, inv_c);

    // 3) S = (a_n . o_n^T)  -> buf1   (opinion_see_aspect = S^T, computed once)
    gemm_nt<<<dim3(L / TBN, L / TBM, NB), 256, 0, stream>>>(
        aspect_int, 2 * F, sAO, opinion_int, 2 * F, sAO, buf1, L, LL, F, inv_a, inv_o);

    // 4) attA = softmask(S) -> buf2 ; attO = softmask(S^T) -> buf3
    softmask_rows<<<NB * L, 256, 0, stream>>>(buf1, mask, buf2);
    colsum_denomO<<<dim3(L / 256, NB), 256, 0, stream>>>(buf1, mask, denomO);
    make_attO<<<dim3(L / 64, L / 64, NB), 256, 0, stream>>>(buf1, mask, denomO, buf3);

    // 5) weigh GEMMs -> second halves of interact slots
    gemm_nn<<<dim3(F / TBN, L / TBM, NB), 256, 0, stream>>>(
        buf2, L, LL, opinion_int, 2 * F, sAO, nullptr, 0, 0, aspect_int + F, 2 * F, sAO, L);
    gemm_nn<<<dim3(F / TBN, L / TBM, NB), 256, 0, stream>>>(
        buf3, L, LL, aspect_int, 2 * F, sAO, nullptr, 0, 0, opinion_int + F, 2 * F, sAO, L);

    // 6) aspect/opinion predictions (+ opinion confidence)
    pred3<<<(NB * L) / 4, 256, 0, stream>>>(aspect_int, 2 * F, 2 * F, Wda, bda, aspect_pred, nullptr);
    pred3<<<(NB * L) / 4, 256, 0, stream>>>(opinion_int, 2 * F, 2 * F, Wdo, bdo, opinion_pred, conf);

    // 7) rank-1 collapse of opinion_propagated: conf[b,i] * Sb[b] * colsum(pos_att)[b,k]
    colsum_pos<<<dim3(L / 256, NB), 256, 0, stream>>>(pos_att, Pb);
    rowsum_mask<<<NB, 256, 0, stream>>>(mask, Sbv);

    // 8) WSC1 = cq . c_n^T -> buf3
    gemm_nt<<<dim3(L / TBN, L / TBM, NB), 256, 0, stream>>>(
        context_q, E, sE, context_conv, E, sE, buf3, L, LL, E, nullptr, inv_c);

    // 9) WSC2 = WSC1 @ pos_att -> buf1
    gemm_nn<<<dim3(L / TBN, L / TBM, NB), 256, 0, stream>>>(
        buf3, L, LL, pos_att, L, LL, nullptr, 0, 0, buf1, L, LL, L);

    // 10) combined attention (in place, buf1)
    combined_att<<<NB * L, 256, 0, stream>>>(buf1, buf2, mask, conf, Sbv, Pb);

    // 11) context_interact = cq + combined @ context_conv
    gemm_nn<<<dim3(E / TBN, L / TBM, NB), 256, 0, stream>>>(
        buf1, L, LL, context_conv, E, sE, context_q, E, sE, context_int, E, sE, L);

    // 12) sentiment prediction
    pred3<<<(NB * L) / 4, 256, 0, stream>>>(context_int, E, E, Wds, bds, sentiment_pred, nullptr);
}

// Round 4
// 1375.097 us; speedup vs baseline: 2.3134x; 1.4544x over previous
//
#include <hip/hip_runtime.h>
#include <math.h>

namespace {

constexpr int NB = 32;     // batch
constexpr int L  = 512;
constexpr int E  = 768;
constexpr int F  = 512;
constexpr float EPS = 1e-7f;

constexpr int TBM = 64, TBN = 64, TBK = 16;

typedef __attribute__((ext_vector_type(8))) short bfrag8;   // 8 bf16 (4 VGPRs)
typedef __attribute__((ext_vector_type(4))) float f32x4;    // MFMA accumulator

// LDS row pitch for 32-k bf16 tiles: 40 shorts = 80 B = 20 dwords.
// bank quad = (5*row + chunk) mod 8 -> all 8 quads hit uniformly, 16B aligned.
constexpr int PITCH = 40;

__device__ __forceinline__ float waveSum(float v) {
#pragma unroll
    for (int off = 32; off > 0; off >>= 1) v += __shfl_down(v, off, 64);
    return v;
}
__device__ __forceinline__ float waveMax(float v) {
#pragma unroll
    for (int off = 32; off > 0; off >>= 1) v = fmaxf(v, __shfl_down(v, off, 64));
    return v;
}

// split 8 fp32 -> 8 bf16 hi (packed uint4) + 8 bf16 lo (packed uint4).
// hi = truncate-to-bf16; lo = truncate-to-bf16(f - hi). err ~3*2^-16 relative.
__device__ __forceinline__ void split8(const float* f, uint4& hi, uint4& lo) {
    unsigned h[8], l[8];
#pragma unroll
    for (int i = 0; i < 8; ++i) {
        const unsigned x = __float_as_uint(f[i]);
        const unsigned hb = x & 0xffff0000u;
        h[i] = hb;
        const float r = f[i] - __uint_as_float(hb);
        l[i] = __float_as_uint(r) & 0xffff0000u;
    }
    hi = make_uint4((h[0] >> 16) | h[1], (h[2] >> 16) | h[3],
                    (h[4] >> 16) | h[5], (h[6] >> 16) | h[7]);
    lo = make_uint4((l[0] >> 16) | l[1], (l[2] >> 16) | l[3],
                    (l[4] >> 16) | l[5], (l[6] >> 16) | l[7]);
}

__device__ __forceinline__ void split4(const float* f, ushort4& h4, ushort4& l4) {
    unsigned h[4], l[4];
#pragma unroll
    for (int i = 0; i < 4; ++i) {
        const unsigned x = __float_as_uint(f[i]);
        const unsigned hb = x & 0xffff0000u;
        h[i] = hb >> 16;
        const float r = f[i] - __uint_as_float(hb);
        l[i] = __float_as_uint(r) >> 16;
    }
    h4 = make_ushort4(h[0], h[1], h[2], h[3]);
    l4 = make_ushort4(l[0], l[1], l[2], l[3]);
}

// =====================================================================
// ===================  FAST PATH (needs ~269 MB ws)  ==================
// =====================================================================

// W [3,E,Cout] fp32 viewed [2304][Cout] -> Wt hi/lo bf16 [Cout][2304]
__global__ __launch_bounds__(256)
void transW(const float* __restrict__ Wsrc, int C,
            ushort* __restrict__ Th, ushort* __restrict__ Tl)
{
    __shared__ float tl[64][65];
    const int k0 = blockIdx.y * 64;
    const int c0 = blockIdx.x * 64;
    const int tx = threadIdx.x & 15, ty = threadIdx.x >> 4;
#pragma unroll
    for (int rr = 0; rr < 4; ++rr) {
        const int r = rr * 16 + ty;
        const float4 v = *(const float4*)&Wsrc[(size_t)(k0 + r) * C + c0 + tx * 4];
        tl[r][tx * 4 + 0] = v.x; tl[r][tx * 4 + 1] = v.y;
        tl[r][tx * 4 + 2] = v.z; tl[r][tx * 4 + 3] = v.w;
    }
    __syncthreads();
#pragma unroll
    for (int rr = 0; rr < 4; ++rr) {
        const int r = rr * 16 + ty;            // local c index
        float f[4];
#pragma unroll
        for (int q = 0; q < 4; ++q) f[q] = tl[tx * 4 + q][r];
        ushort4 h4, l4;
        split4(f, h4, l4);
        *(ushort4*)&Th[(size_t)(c0 + r) * 2304 + k0 + tx * 4] = h4;
        *(ushort4*)&Tl[(size_t)(c0 + r) * 2304 + k0 + tx * 4] = l4;
    }
}

// batched fp32 transpose: src [R][C] (ld=lin) -> dst [C][R] (ld=ldd)
__global__ __launch_bounds__(256)
void transpose_f32(const float* __restrict__ src, int lin, long long sS,
                   float* __restrict__ dst, int ldd, long long sD)
{
    __shared__ float tl[64][65];
    const int b = blockIdx.z;
    const int r0 = blockIdx.y * 64;
    const int c0 = blockIdx.x * 64;
    const float* s = src + (size_t)b * sS;
    float* d = dst + (size_t)b * sD;
    const int tx = threadIdx.x & 15, ty = threadIdx.x >> 4;
#pragma unroll
    for (int rr = 0; rr < 4; ++rr) {
        const int r = rr * 16 + ty;
        const float4 v = *(const float4*)&s[(size_t)(r0 + r) * lin + c0 + tx * 4];
        tl[r][tx * 4 + 0] = v.x; tl[r][tx * 4 + 1] = v.y;
        tl[r][tx * 4 + 2] = v.z; tl[r][tx * 4 + 3] = v.w;
    }
    __syncthreads();
#pragma unroll
    for (int rr = 0; rr < 4; ++rr) {
        const int r = rr * 16 + ty;            // local c index
        float4 o;
        o.x = tl[tx * 4 + 0][r]; o.y = tl[tx * 4 + 1][r];
        o.z = tl[tx * 4 + 2][r]; o.w = tl[tx * 4 + 3][r];
        *(float4*)&d[(size_t)(c0 + r) * ldd + r0 + tx * 4] = o;
    }
}

// Unified batched split-bf16 MFMA GEMM: C = (A . B^T) with optional per-row /
// per-col scales and fp32 residual. A [M=512][K] row-major, B [N][K] row-major.
// 128x128 tile, BK=32, 4 waves (2x2 of 64x64), padded LDS (PITCH=40).
// XCD-chunked flat grid: 4 batches per XCD.
__global__ __launch_bounds__(256, 2)
void gemm_bf3(const float* __restrict__ A, int lda, long long sA,
              const float* __restrict__ B, int ldb, long long sB,
              const float* __restrict__ sa, const float* __restrict__ sb,
              const float* __restrict__ R, int ldr, long long sR,
              float* __restrict__ C, int ldc, long long sC,
              int K, int Nb)
{
    __shared__ __align__(16) short Ah[128 * PITCH];
    __shared__ __align__(16) short Al[128 * PITCH];
    __shared__ __align__(16) short Bh[128 * PITCH];
    __shared__ __align__(16) short Bl[128 * PITCH];

    const int id  = blockIdx.x;
    const int xcd = id & 7, idx = id >> 3;
    const int wpb = 4 * Nb;                       // M blocks = 4 (M = 512)
    const int bz  = xcd * 4 + idx / wpb;
    const int w   = idx % wpb;
    const int m0  = (w / Nb) * 128;
    const int n0  = (w % Nb) * 128;

    const float* Ab = A + (size_t)bz * sA;
    const float* Bb = B + (size_t)bz * sB;

    const int t = threadIdx.x;
    const int lane = t & 63, wid = t >> 6;
    const int wm = (wid & 2) * 32, wn = (wid & 1) * 64;
    const int row = t >> 1, half = t & 1;
    const int rl = lane & 15;
    const int kc = (lane >> 4) * 8;               // k-chunk offset in shorts

    f32x4 acc[4][4] = {};

    for (int k0 = 0; k0 < K; k0 += 32) {
        const float* ap = Ab + (size_t)(m0 + row) * lda + k0 + half * 16;
        const float* bp = Bb + (size_t)(n0 + row) * ldb + k0 + half * 16;
        float av[16], bv[16];
#pragma unroll
        for (int q = 0; q < 4; ++q) {
            const float4 v = *(const float4*)(ap + q * 4);
            av[q * 4 + 0] = v.x; av[q * 4 + 1] = v.y;
            av[q * 4 + 2] = v.z; av[q * 4 + 3] = v.w;
            const float4 u = *(const float4*)(bp + q * 4);
            bv[q * 4 + 0] = u.x; bv[q * 4 + 1] = u.y;
            bv[q * 4 + 2] = u.z; bv[q * 4 + 3] = u.w;
        }
        uint4 ah0, al0, ah1, al1, bh0, bl0, bh1, bl1;
        split8(av + 0, ah0, al0); split8(av + 8, ah1, al1);
        split8(bv + 0, bh0, bl0); split8(bv + 8, bh1, bl1);

        __syncthreads();
        const int base = row * PITCH + half * 16;
        *(uint4*)&Ah[base]     = ah0; *(uint4*)&Ah[base + 8] = ah1;
        *(uint4*)&Al[base]     = al0; *(uint4*)&Al[base + 8] = al1;
        *(uint4*)&Bh[base]     = bh0; *(uint4*)&Bh[base + 8] = bh1;
        *(uint4*)&Bl[base]     = bl0; *(uint4*)&Bl[base + 8] = bl1;
        __syncthreads();

        bfrag8 fah[4], fal[4], fbh[4], fbl[4];
#pragma unroll
        for (int i = 0; i < 4; ++i) {
            const int ra = (wm + i * 16 + rl) * PITCH + kc;
            fah[i] = *(const bfrag8*)&Ah[ra];
            fal[i] = *(const bfrag8*)&Al[ra];
            const int rb = (wn + i * 16 + rl) * PITCH + kc;
            fbh[i] = *(const bfrag8*)&Bh[rb];
            fbl[i] = *(const bfrag8*)&Bl[rb];
        }
#pragma unroll
        for (int i = 0; i < 4; ++i)
#pragma unroll
            for (int j = 0; j < 4; ++j) {
                acc[i][j] = __builtin_amdgcn_mfma_f32_16x16x32_bf16(
                    fah[i], fbh[j], acc[i][j], 0, 0, 0);
                acc[i][j] = __builtin_amdgcn_mfma_f32_16x16x32_bf16(
                    fal[i], fbh[j], acc[i][j], 0, 0, 0);
                acc[i][j] = __builtin_amdgcn_mfma_f32_16x16x32_bf16(
                    fah[i], fbl[j], acc[i][j], 0, 0, 0);
            }
    }

    // epilogue
    const int rb = m0 + wm + (lane >> 4) * 4;
    const int cb = n0 + wn + rl;
    float srv[16];
#pragma unroll
    for (int i = 0; i < 4; ++i)
#pragma unroll
        for (int g = 0; g < 4; ++g)
            srv[i * 4 + g] = sa ? sa[bz * L + rb + i * 16 + g] : 1.f;
#pragma unroll
    for (int j = 0; j < 4; ++j) {
        const int col = cb + j * 16;
        const float scb = sb ? sb[bz * L + col] : 1.f;
#pragma unroll
        for (int i = 0; i < 4; ++i) {
#pragma unroll
            for (int g = 0; g < 4; ++g) {
                const int rr = rb + i * 16 + g;
                float v = acc[i][j][g] * srv[i * 4 + g] * scb;
                if (R) v += R[(size_t)bz * sR + (size_t)rr * ldr + col];
                C[(size_t)bz * sC + (size_t)rr * ldc + col] = v;
            }
        }
    }
}

// conv1d (K=3, SAME) with pre-split/transposed weights Wt [Cout][3E] bf16 hi/lo.
// A staged fp32->split on the fly; B staged by linear bf16 vector loads.
// XCD-chunked grid: each XCD owns 16 contiguous row-blocks (x all col-blocks).
__global__ __launch_bounds__(256, 2)
void conv_mfma_wt(const float* __restrict__ X,      // [NB,L,E] fp32
                  const ushort* __restrict__ Wth,   // [Cout][2304] bf16 hi
                  const ushort* __restrict__ Wtl,   // [Cout][2304] bf16 lo
                  const float* __restrict__ bias,
                  float* __restrict__ Out, int ldo)
{
    __shared__ __align__(16) short Ah[128 * PITCH];
    __shared__ __align__(16) short Al[128 * PITCH];
    __shared__ __align__(16) short Bh[128 * PITCH];
    __shared__ __align__(16) short Bl[128 * PITCH];

    const int id  = blockIdx.x;
    const int xcd = id & 7, idx = id >> 3;
    const int m0  = (xcd * 16 + (idx & 15)) * 128;
    const int n0  = (idx >> 4) * 128;

    const int t = threadIdx.x;
    const int lane = t & 63, wid = t >> 6;
    const int wm = (wid & 2) * 32, wn = (wid & 1) * 64;
    const int row = t >> 1, half = t & 1;
    const int rl = lane & 15;
    const int kc = (lane >> 4) * 8;

    const int b  = m0 >> 9;
    const int lb = m0 & (L - 1);

    f32x4 acc[4][4] = {};

    for (int kk = 0; kk < 3; ++kk) {
        const int l = lb + row + kk - 1;
        const bool valid = (l >= 0) && (l < L);
        const float* arow = X + ((size_t)b * L + (valid ? l : 0)) * E + half * 16;
        const ushort* bhp = Wth + (size_t)(n0 + row) * 2304 + kk * E + half * 16;
        const ushort* blp = Wtl + (size_t)(n0 + row) * 2304 + kk * E + half * 16;

        for (int e0 = 0; e0 < E; e0 += 32) {
            float av[16];
#pragma unroll
            for (int q = 0; q < 4; ++q) {
                const float4 v = valid ? *(const float4*)(arow + e0 + q * 4)
                                       : make_float4(0.f, 0.f, 0.f, 0.f);
                av[q * 4 + 0] = v.x; av[q * 4 + 1] = v.y;
                av[q * 4 + 2] = v.z; av[q * 4 + 3] = v.w;
            }
            uint4 ah0, al0, ah1, al1;
            split8(av + 0, ah0, al0); split8(av + 8, ah1, al1);
            const uint4 bh0 = *(const uint4*)(bhp + e0);
            const uint4 bh1 = *(const uint4*)(bhp + e0 + 8);
            const uint4 bl0 = *(const uint4*)(blp + e0);
            const uint4 bl1 = *(const uint4*)(blp + e0 + 8);

            __syncthreads();
            const int base = row * PITCH + half * 16;
            *(uint4*)&Ah[base]     = ah0; *(uint4*)&Ah[base + 8] = ah1;
            *(uint4*)&Al[base]     = al0; *(uint4*)&Al[base + 8] = al1;
            *(uint4*)&Bh[base]     = bh0; *(uint4*)&Bh[base + 8] = bh1;
            *(uint4*)&Bl[base]     = bl0; *(uint4*)&Bl[base + 8] = bl1;
            __syncthreads();

            bfrag8 fah[4], fal[4], fbh[4], fbl[4];
#pragma unroll
            for (int i = 0; i < 4; ++i) {
                const int ra = (wm + i * 16 + rl) * PITCH + kc;
                fah[i] = *(const bfrag8*)&Ah[ra];
                fal[i] = *(const bfrag8*)&Al[ra];
                const int rbq = (wn + i * 16 + rl) * PITCH + kc;
                fbh[i] = *(const bfrag8*)&Bh[rbq];
                fbl[i] = *(const bfrag8*)&Bl[rbq];
            }
#pragma unroll
            for (int i = 0; i < 4; ++i)
#pragma unroll
                for (int j = 0; j < 4; ++j) {
                    acc[i][j] = __builtin_amdgcn_mfma_f32_16x16x32_bf16(
                        fah[i], fbh[j], acc[i][j], 0, 0, 0);
                    acc[i][j] = __builtin_amdgcn_mfma_f32_16x16x32_bf16(
                        fal[i], fbh[j], acc[i][j], 0, 0, 0);
                    acc[i][j] = __builtin_amdgcn_mfma_f32_16x16x32_bf16(
                        fah[i], fbl[j], acc[i][j], 0, 0, 0);
                }
        }
    }

    const int rbase = m0 + wm + (lane >> 4) * 4;
    const int cbase = n0 + wn + rl;
#pragma unroll
    for (int j = 0; j < 4; ++j) {
        const float bj = bias[cbase + j * 16];
#pragma unroll
        for (int i = 0; i < 4; ++i)
#pragma unroll
            for (int g = 0; g < 4; ++g) {
                const int rr = rbase + i * 16 + g;
                Out[(size_t)rr * ldo + cbase + j * 16] =
                    fmaxf(acc[i][j][g] + bj, 0.f);
            }
    }
}

// =====================================================================
// ============  FALLBACK PATH kernels (round-2, proven)  ==============
// =====================================================================

__global__ __launch_bounds__(256, 2)
void conv_mfma(const float* __restrict__ X, const float* __restrict__ W,
               const float* __restrict__ bias, float* __restrict__ Out,
               int Cout, int ldo)
{
    __shared__ __align__(16) short Ah[128 * 32];
    __shared__ __align__(16) short Al[128 * 32];
    __shared__ __align__(16) short Bh[128 * 32];
    __shared__ __align__(16) short Bl[128 * 32];

    const int t = threadIdx.x;
    const int lane = t & 63;
    const int wid = t >> 6;
    const int wm = (wid & 2) * 32;
    const int wn = (wid & 1) * 64;
    const int m0 = blockIdx.y * 128;
    const int n0 = blockIdx.x * 128;

    const int ar = t >> 1;
    const int ah_half = t & 1;
    const int bn = t & 127;
    const int bk_half = t >> 7;

    const int rl = lane & 15;
    const int chl = ((lane >> 4) ^ (lane & 3)) << 3;

    f32x4 acc[4][4] = {};

    for (int kk = 0; kk < 3; ++kk) {
        const int m = m0 + ar;
        const int bb = m >> 9;
        const int ll = (m & (L - 1)) + kk - 1;
        const bool valid = (ll >= 0) && (ll < L);
        const float* arow = X + ((size_t)bb * L + (valid ? ll : 0)) * E + ah_half * 16;

        for (int e0 = 0; e0 < E; e0 += 32) {
            float av[16];
            const float4* ap = (const float4*)(arow + e0);
#pragma unroll
            for (int q = 0; q < 4; ++q) {
                float4 v = valid ? ap[q] : make_float4(0.f, 0.f, 0.f, 0.f);
                av[q * 4 + 0] = v.x; av[q * 4 + 1] = v.y;
                av[q * 4 + 2] = v.z; av[q * 4 + 3] = v.w;
            }
            float bv[16];
            const float* bp = W + ((size_t)(kk * E + e0 + bk_half * 16)) * Cout + n0 + bn;
#pragma unroll
            for (int i = 0; i < 16; ++i) bv[i] = bp[(size_t)i * Cout];

            uint4 h0, l0, h1, l1;
            split8(av + 0, h0, l0);
            split8(av + 8, h1, l1);
            uint4 g0, m0v, g1, m1v;
            split8(bv + 0, g0, m0v);
            split8(bv + 8, g1, m1v);

            __syncthreads();
            {
                const int c0 = ah_half * 2;
                const int s0 = ((c0 ^ (ar & 3)) << 3);
                const int s1 = (((c0 + 1) ^ (ar & 3)) << 3);
                *(uint4*)&Ah[ar * 32 + s0] = h0;
                *(uint4*)&Al[ar * 32 + s0] = l0;
                *(uint4*)&Ah[ar * 32 + s1] = h1;
                *(uint4*)&Al[ar * 32 + s1] = l1;
                const int d0 = bk_half * 2;
                const int u0 = ((d0 ^ (bn & 3)) << 3);
                const int u1 = (((d0 + 1) ^ (bn & 3)) << 3);
                *(uint4*)&Bh[bn * 32 + u0] = g0;
                *(uint4*)&Bl[bn * 32 + u0] = m0v;
                *(uint4*)&Bh[bn * 32 + u1] = g1;
                *(uint4*)&Bl[bn * 32 + u1] = m1v;
            }
            __syncthreads();

            bfrag8 fah[4], fal[4], fbh[4], fbl[4];
#pragma unroll
            for (int i = 0; i < 4; ++i) {
                const int rowa = (wm + i * 16 + rl) * 32 + chl;
                fah[i] = *(const bfrag8*)&Ah[rowa];
                fal[i] = *(const bfrag8*)&Al[rowa];
                const int rowb = (wn + i * 16 + rl) * 32 + chl;
                fbh[i] = *(const bfrag8*)&Bh[rowb];
                fbl[i] = *(const bfrag8*)&Bl[rowb];
            }
#pragma unroll
            for (int i = 0; i < 4; ++i)
#pragma unroll
                for (int j = 0; j < 4; ++j) {
                    acc[i][j] = __builtin_amdgcn_mfma_f32_16x16x32_bf16(
                        fah[i], fbh[j], acc[i][j], 0, 0, 0);
                    acc[i][j] = __builtin_amdgcn_mfma_f32_16x16x32_bf16(
                        fal[i], fbh[j], acc[i][j], 0, 0, 0);
                    acc[i][j] = __builtin_amdgcn_mfma_f32_16x16x32_bf16(
                        fah[i], fbl[j], acc[i][j], 0, 0, 0);
                }
        }
    }

    const int rbase = m0 + wm + (lane >> 4) * 4;
    const int cbase = n0 + wn + (lane & 15);
#pragma unroll
    for (int j = 0; j < 4; ++j) {
        const float bj = bias[cbase + j * 16];
#pragma unroll
        for (int i = 0; i < 4; ++i) {
#pragma unroll
            for (int g = 0; g < 4; ++g) {
                const int rr = rbase + i * 16 + g;
                Out[(size_t)rr * ldo + cbase + j * 16] = fmaxf(acc[i][j][g] + bj, 0.f);
            }
        }
    }
}

__global__ __launch_bounds__(256)
void gemm_nt(const float* __restrict__ A, int lda, long long sA,
             const float* __restrict__ Bm, int ldb, long long sB,
             float* __restrict__ Cc, int ldc, long long sC, int K,
             const float* __restrict__ sa, const float* __restrict__ sb)
{
    __shared__ float As[TBK][TBM];
    __shared__ float Bs[TBK][TBN];
    const int bz = blockIdx.z;
    const float* Ab = A + (size_t)bz * sA;
    const float* Bb = Bm + (size_t)bz * sB;
    float* Cb = Cc + (size_t)bz * sC;
    const int tid = threadIdx.x;
    const int tx = tid & 15, ty = tid >> 4;
    const int m0 = blockIdx.y * TBM, n0 = blockIdx.x * TBN;
    const int mi = tid >> 2;
    const int pe = (tid & 3) << 2;

    float acc[4][4] = {};
    for (int k0 = 0; k0 < K; k0 += TBK) {
        const float4 av = *(const float4*)&Ab[(size_t)(m0 + mi) * lda + k0 + pe];
        As[pe + 0][mi] = av.x; As[pe + 1][mi] = av.y;
        As[pe + 2][mi] = av.z; As[pe + 3][mi] = av.w;
        const float4 bv = *(const float4*)&Bb[(size_t)(n0 + mi) * ldb + k0 + pe];
        Bs[pe + 0][mi] = bv.x; Bs[pe + 1][mi] = bv.y;
        Bs[pe + 2][mi] = bv.z; Bs[pe + 3][mi] = bv.w;
        __syncthreads();
#pragma unroll
        for (int p = 0; p < TBK; ++p) {
            const float4 a4 = *(const float4*)&As[p][ty << 2];
            const float4 b4 = *(const float4*)&Bs[p][tx << 2];
            const float ar[4] = {a4.x, a4.y, a4.z, a4.w};
            const float br[4] = {b4.x, b4.y, b4.z, b4.w};
#pragma unroll
            for (int i = 0; i < 4; ++i)
#pragma unroll
                for (int j = 0; j < 4; ++j) acc[i][j] += ar[i] * br[j];
        }
        __syncthreads();
    }
    float sr[4], sc[4];
#pragma unroll
    for (int i = 0; i < 4; ++i)
        sr[i] = sa ? sa[bz * L + m0 + (ty << 2) + i] : 1.f;
#pragma unroll
    for (int j = 0; j < 4; ++j)
        sc[j] = sb ? sb[bz * L + n0 + (tx << 2) + j] : 1.f;
#pragma unroll
    for (int i = 0; i < 4; ++i) {
        float4 o;
        o.x = acc[i][0] * sr[i] * sc[0];
        o.y = acc[i][1] * sr[i] * sc[1];
        o.z = acc[i][2] * sr[i] * sc[2];
        o.w = acc[i][3] * sr[i] * sc[3];
        *(float4*)&Cb[(size_t)(m0 + (ty << 2) + i) * ldc + n0 + (tx << 2)] = o;
    }
}

__global__ __launch_bounds__(256)
void gemm_nn(const float* __restrict__ A, int lda, long long sA,
             const float* __restrict__ Bm, int ldb, long long sB,
             const float* __restrict__ R, int ldr, long long sR,
             float* __restrict__ Cc, int ldc, long long sC, int K)
{
    __shared__ float As[TBK][TBM];
    __shared__ float Bs[TBK][TBN];
    const int bz = blockIdx.z;
    const float* Ab = A + (size_t)bz * sA;
    const float* Bb = Bm + (size_t)bz * sB;
    float* Cb = Cc + (size_t)bz * sC;
    const int tid = threadIdx.x;
    const int tx = tid & 15, ty = tid >> 4;
    const int m0 = blockIdx.y * TBM, n0 = blockIdx.x * TBN;
    const int mi = tid >> 2;
    const int pe = (tid & 3) << 2;
    const int pi = tid >> 4;
    const int fi = (tid & 15) << 2;

    float acc[4][4] = {};
    for (int k0 = 0; k0 < K; k0 += TBK) {
        const float4 av = *(const float4*)&Ab[(size_t)(m0 + mi) * lda + k0 + pe];
        As[pe + 0][mi] = av.x; As[pe + 1][mi] = av.y;
        As[pe + 2][mi] = av.z; As[pe + 3][mi] = av.w;
        *(float4*)&Bs[pi][fi] = *(const float4*)&Bb[(size_t)(k0 + pi) * ldb + n0 + fi];
        __syncthreads();
#pragma unroll
        for (int p = 0; p < TBK; ++p) {
            const float4 a4 = *(const float4*)&As[p][ty << 2];
            const float4 b4 = *(const float4*)&Bs[p][tx << 2];
            const float ar[4] = {a4.x, a4.y, a4.z, a4.w};
            const float br[4] = {b4.x, b4.y, b4.z, b4.w};
#pragma unroll
            for (int i = 0; i < 4; ++i)
#pragma unroll
                for (int j = 0; j < 4; ++j) acc[i][j] += ar[i] * br[j];
        }
        __syncthreads();
    }
#pragma unroll
    for (int i = 0; i < 4; ++i) {
        const int m = m0 + (ty << 2) + i;
        const int n = n0 + (tx << 2);
        float4 o = make_float4(acc[i][0], acc[i][1], acc[i][2], acc[i][3]);
        if (R) {
            const float4 r = *(const float4*)&R[(size_t)bz * sR + (size_t)m * ldr + n];
            o.x += r.x; o.y += r.y; o.z += r.z; o.w += r.w;
        }
        *(float4*)&Cb[(size_t)m * ldc + n] = o;
    }
}

// =====================================================================
// ======================  shared small kernels  =======================
// =====================================================================

__global__ __launch_bounds__(256)
void inv_l2norm(const float* __restrict__ Xp, int len, int ld, float* __restrict__ inv)
{
    __shared__ float red[4];
    const int m = blockIdx.x;
    const float* row = Xp + (size_t)m * ld;
    float s = 0.f;
    for (int h = threadIdx.x; h < len; h += 256) { const float v = row[h]; s += v * v; }
    s = waveSum(s);
    const int lane = threadIdx.x & 63, wid = threadIdx.x >> 6;
    if (lane == 0) red[wid] = s;
    __syncthreads();
    if (threadIdx.x == 0)
        inv[m] = 1.0f / sqrtf(fmaxf(red[0] + red[1] + red[2] + red[3], 1e-12f));
}

__global__ __launch_bounds__(256)
void softmask_rows(const float* __restrict__ S, const float* __restrict__ mask,
                   float* __restrict__ att)
{
    __shared__ float red[4];
    const int row = blockIdx.x;
    const int b = row >> 9;
    const int i = row & (L - 1);
    const float* s_ = S + (size_t)row * L;
    float* a_ = att + (size_t)row * L;
    const int t = threadIdx.x;
    const int lane = t & 63, wid = t >> 6;
    const float e0 = expf(s_[t]) * mask[b * L + t];
    const float e1 = expf(s_[t + 256]) * mask[b * L + t + 256];
    float s = waveSum(e0 + e1);
    if (lane == 0) red[wid] = s;
    __syncthreads();
    const float tot = red[0] + red[1] + red[2] + red[3];
    const float sc = mask[b * L + i] / (tot + EPS);
    a_[t] = e0 * sc;
    a_[t + 256] = e1 * sc;
}

__global__ __launch_bounds__(256)
void colsum_denomO(const float* __restrict__ S, const float* __restrict__ mask,
                   float* __restrict__ denomO)
{
    const int b = blockIdx.y;
    const int i = blockIdx.x * 256 + threadIdx.x;
    const float* Sb_ = S + (size_t)b * L * L;
    float s = 0.f;
    for (int j = 0; j < L; ++j) s += expf(Sb_[(size_t)j * L + i]) * mask[b * L + j];
    denomO[b * L + i] = s + EPS;
}

__global__ __launch_bounds__(256)
void make_attO(const float* __restrict__ S, const float* __restrict__ mask,
               const float* __restrict__ denomO, float* __restrict__ attO)
{
    __shared__ float tt[64][65];
    const int b = blockIdx.z;
    const int i0 = blockIdx.y * 64;
    const int j0 = blockIdx.x * 64;
    const float* Sb_ = S + (size_t)b * L * L;
    float* Ob = attO + (size_t)b * L * L;
    const int tx = threadIdx.x & 15, ty = threadIdx.x >> 4;
#pragma unroll
    for (int rr = 0; rr < 4; ++rr) {
        const int r = rr * 16 + ty;
        const float4 v = *(const float4*)&Sb_[(size_t)(j0 + r) * L + i0 + tx * 4];
        tt[r][tx * 4 + 0] = v.x; tt[r][tx * 4 + 1] = v.y;
        tt[r][tx * 4 + 2] = v.z; tt[r][tx * 4 + 3] = v.w;
    }
    __syncthreads();
#pragma unroll
    for (int rr = 0; rr < 4; ++rr) {
        const int r = rr * 16 + ty;
        const int i = i0 + r;
        const int c = tx * 4;
        const float mi_d = mask[b * L + i] / denomO[b * L + i];
        float4 o;
        o.x = expf(tt[c + 0][r]) * mask[b * L + j0 + c + 0] * mi_d;
        o.y = expf(tt[c + 1][r]) * mask[b * L + j0 + c + 1] * mi_d;
        o.z = expf(tt[c + 2][r]) * mask[b * L + j0 + c + 2] * mi_d;
        o.w = expf(tt[c + 3][r]) * mask[b * L + j0 + c + 3] * mi_d;
        *(float4*)&Ob[(size_t)i * L + j0 + c] = o;
    }
}

__global__ __launch_bounds__(256)
void pred3(const float* __restrict__ In, int ldi, int K,
           const float* __restrict__ Wd, const float* __restrict__ bd,
           float* __restrict__ pred, float* __restrict__ conf)
{
    __shared__ float sW[3 * 1024];
    for (int t = threadIdx.x; t < K * 3; t += 256) sW[t] = Wd[t];
    __syncthreads();
    const int wid = threadIdx.x >> 6, lane = threadIdx.x & 63;
    const int m = blockIdx.x * 4 + wid;
    const float* row = In + (size_t)m * ldi;
    float a0 = 0.f, a1 = 0.f, a2 = 0.f;
    for (int h = lane; h < K; h += 64) {
        const float v = row[h];
        a0 += v * sW[h * 3 + 0];
        a1 += v * sW[h * 3 + 1];
        a2 += v * sW[h * 3 + 2];
    }
    a0 = waveSum(a0); a1 = waveSum(a1); a2 = waveSum(a2);
    if (lane == 0) {
        a0 += bd[0]; a1 += bd[1]; a2 += bd[2];
        pred[(size_t)m * 3 + 0] = a0;
        pred[(size_t)m * 3 + 1] = a1;
        pred[(size_t)m * 3 + 2] = a2;
        if (conf) {
            const float mx = fmaxf(a0, fmaxf(a1, a2));
            const float z0 = expf(a0 - mx), z1 = expf(a1 - mx), z2 = expf(a2 - mx);
            const float p0 = z0 / (z0 + z1 + z2);
            conf[m] = fmaxf(0.f, 1.f - 2.f * p0);
        }
    }
}

__global__ __launch_bounds__(256)
void colsum_pos(const float* __restrict__ P, float* __restrict__ Pb)
{
    const int b = blockIdx.y;
    const int k = blockIdx.x * 256 + threadIdx.x;
    const float* p = P + (size_t)b * L * L;
    float s = 0.f;
    for (int j = 0; j < L; ++j) s += p[(size_t)j * L + k];
    Pb[b * L + k] = s;
}

__global__ __launch_bounds__(256)
void rowsum_mask(const float* __restrict__ mask, float* __restrict__ Sb)
{
    __shared__ float red[4];
    const int b = blockIdx.x;
    float s = 0.f;
    for (int j = threadIdx.x; j < L; j += 256) s += mask[b * L + j];
    s = waveSum(s);
    const int lane = threadIdx.x & 63, wid = threadIdx.x >> 6;
    if (lane == 0) red[wid] = s;
    __syncthreads();
    if (threadIdx.x == 0) Sb[b] = red[0] + red[1] + red[2] + red[3];
}

__global__ __launch_bounds__(256)
void combined_att(float* __restrict__ WSC2, const float* __restrict__ attA,
                  const float* __restrict__ mask, const float* __restrict__ conf,
                  const float* __restrict__ Sb, const float* __restrict__ Pb)
{
    __shared__ float red[4];
    const int row = blockIdx.x;
    const int b = row >> 9;
    const int i = row & (L - 1);
    float* x = WSC2 + (size_t)row * L;
    const float* aA = attA + (size_t)row * L;
    const int t = threadIdx.x;
    const int lane = t & 63, wid = t >> 6;
    const float x0 = x[t], x1 = x[t + 256];
    float v = waveMax(fmaxf(x0, x1));
    if (lane == 0) red[wid] = v;
    __syncthreads();
    const float mx = fmaxf(fmaxf(red[0], red[1]), fmaxf(red[2], red[3]));
    const float e0 = expf(x0 - mx) * mask[b * L + t];
    const float e1 = expf(x1 - mx) * mask[b * L + t + 256];
    float s = waveSum(e0 + e1);
    __syncthreads();
    if (lane == 0) red[wid] = s;
    __syncthreads();
    const float tot = red[0] + red[1] + red[2] + red[3];
    const float sc = mask[b * L + i] / (tot + EPS);
    const float add = conf[row] * Sb[b];
    x[t]       = e0 * sc + aA[t]       + add * Pb[b * L + t];
    x[t + 256] = e1 * sc + aA[t + 256] + add * Pb[b * L + t + 256];
}

} // namespace

extern "C" void kernel_launch(void* const* d_in, const int* in_sizes, int n_in,
                              void* d_out, int out_size, void* d_ws, size_t ws_size,
                              hipStream_t stream)
{
    const float* aspect_in  = (const float*)d_in[0];
    const float* opinion_in = (const float*)d_in[1];
    const float* context_in = (const float*)d_in[2];
    const float* context_q  = (const float*)d_in[3];
    const float* mask       = (const float*)d_in[4];
    const float* pos_att    = (const float*)d_in[5];
    const float* Wa  = (const float*)d_in[6];  const float* ba  = (const float*)d_in[7];
    const float* Wo  = (const float*)d_in[8];  const float* bo  = (const float*)d_in[9];
    const float* Wc  = (const float*)d_in[10]; const float* bc  = (const float*)d_in[11];
    const float* Wda = (const float*)d_in[12]; const float* bda = (const float*)d_in[13];
    const float* Wdo = (const float*)d_in[14]; const float* bdo = (const float*)d_in[15];
    const float* Wds = (const float*)d_in[16]; const float* bds = (const float*)d_in[17];

    float* out = (float*)d_out;
    const size_t BL = (size_t)NB * L;
    float* aspect_pred    = out;
    float* opinion_pred   = out + BL * 3;
    float* sentiment_pred = out + BL * 6;
    float* aspect_int     = out + BL * 9;                 // [BL, 1024]
    float* opinion_int    = aspect_int + BL * 2 * F;      // [BL, 1024]
    float* context_int    = opinion_int + BL * 2 * F;     // [BL, 768]
    float* context_conv   = context_int + BL * E;         // [BL, 768]

    float* ws = (float*)d_ws;
    const long long LL = (long long)L * L;
    const size_t BLL = (size_t)NB * L * L;
    float* buf1   = ws;               // S -> WSC2/combined att
    float* buf2   = buf1 + BLL;       // attA
    float* buf3   = buf2 + BLL;       // attO -> WSC1
    float* inv_a  = buf3 + BLL;
    float* inv_o  = inv_a + BL;
    float* inv_c  = inv_o + BL;
    float* denomO = inv_c + BL;
    float* conf   = denomO + BL;
    float* Pb     = conf + BL;
    float* Sbv    = Pb + BL;

    const long long sAO = (long long)L * 2 * F;
    const long long sE  = (long long)L * E;

    // ------- fast-path extra workspace -------
    float* aT = Sbv + BL + 64;                        // [NB][F][L]
    float* oT = aT + (size_t)NB * F * L;              // [NB][F][L]
    float* cT = oT + (size_t)NB * F * L;              // [NB][E][L]
    float* pT = cT + (size_t)NB * E * L;              // [NB][L][L]
    ushort* Wta_h = (ushort*)(pT + BLL);
    ushort* Wta_l = Wta_h + (size_t)2304 * F;
    ushort* Wto_h = Wta_l + (size_t)2304 * F;
    ushort* Wto_l = Wto_h + (size_t)2304 * F;
    ushort* Wtc_h = Wto_l + (size_t)2304 * F;
    ushort* Wtc_l = Wtc_h + (size_t)2304 * E;
    const size_t ws_need = (size_t)((char*)(Wtc_l + (size_t)2304 * E) - (char*)d_ws);

    if (ws_size >= ws_need) {
        // ================= FAST PATH =================
        transW<<<dim3(F / 64, 36), 256, 0, stream>>>(Wa, F, Wta_h, Wta_l);
        transW<<<dim3(F / 64, 36), 256, 0, stream>>>(Wo, F, Wto_h, Wto_l);
        transW<<<dim3(E / 64, 36), 256, 0, stream>>>(Wc, E, Wtc_h, Wtc_l);

        conv_mfma_wt<<<128 * 4, 256, 0, stream>>>(aspect_in, Wta_h, Wta_l, ba, aspect_int, 2 * F);
        conv_mfma_wt<<<128 * 4, 256, 0, stream>>>(opinion_in, Wto_h, Wto_l, bo, opinion_int, 2 * F);
        conv_mfma_wt<<<128 * 6, 256, 0, stream>>>(context_in, Wtc_h, Wtc_l, bc, context_conv, E);

        inv_l2norm<<<NB * L, 256, 0, stream>>>(aspect_int, F, 2 * F, inv_a);
        inv_l2norm<<<NB * L, 256, 0, stream>>>(opinion_int, F, 2 * F, inv_o);
        inv_l2norm<<<NB * L, 256, 0, stream>>>(context_conv, E, E, inv_c);

        // transposed copies for NN-form GEMMs (B must be [N][K])
        transpose_f32<<<dim3(F / 64, L / 64, NB), 256, 0, stream>>>(
            aspect_int, 2 * F, sAO, aT, L, (long long)F * L);
        transpose_f32<<<dim3(F / 64, L / 64, NB), 256, 0, stream>>>(
            opinion_int, 2 * F, sAO, oT, L, (long long)F * L);
        transpose_f32<<<dim3(E / 64, L / 64, NB), 256, 0, stream>>>(
            context_conv, E, sE, cT, L, (long long)E * L);
        transpose_f32<<<dim3(L / 64, L / 64, NB), 256, 0, stream>>>(
            pos_att, L, LL, pT, L, LL);

        // S = (a . o^T) * inv_a_i * inv_o_j -> buf1
        gemm_bf3<<<32 * 16, 256, 0, stream>>>(
            aspect_int, 2 * F, sAO, opinion_int, 2 * F, sAO,
            inv_a, inv_o, nullptr, 0, 0, buf1, L, LL, F, 4);

        softmask_rows<<<NB * L, 256, 0, stream>>>(buf1, mask, buf2);
        colsum_denomO<<<dim3(L / 256, NB), 256, 0, stream>>>(buf1, mask, denomO);
        make_attO<<<dim3(L / 64, L / 64, NB), 256, 0, stream>>>(buf1, mask, denomO, buf3);

        // weigh GEMMs
        gemm_bf3<<<32 * 16, 256, 0, stream>>>(
            buf2, L, LL, oT, L, (long long)F * L,
            nullptr, nullptr, nullptr, 0, 0, aspect_int + F, 2 * F, sAO, L, 4);
        gemm_bf3<<<32 * 16, 256, 0, stream>>>(
            buf3, L, LL, aT, L, (long long)F * L,
            nullptr, nullptr, nullptr, 0, 0, opinion_int + F, 2 * F, sAO, L, 4);

        pred3<<<(NB * L) / 4, 256, 0, stream>>>(aspect_int, 2 * F, 2 * F, Wda, bda, aspect_pred, nullptr);
        pred3<<<(NB * L) / 4, 256, 0, stream>>>(opinion_int, 2 * F, 2 * F, Wdo, bdo, opinion_pred, conf);

        colsum_pos<<<dim3(L / 256, NB), 256, 0, stream>>>(pos_att, Pb);
        rowsum_mask<<<NB, 256, 0, stream>>>(mask, Sbv);

        // WSC1 = cq . c_n^T -> buf3 (attO dead)
        gemm_bf3<<<32 * 16, 256, 0, stream>>>(
            context_q, E, sE, context_conv, E, sE,
            nullptr, inv_c, nullptr, 0, 0, buf3, L, LL, E, 4);

        // WSC2 = WSC1 @ pos_att -> buf1 (S dead)
        gemm_bf3<<<32 * 16, 256, 0, stream>>>(
            buf3, L, LL, pT, L, LL,
            nullptr, nullptr, nullptr, 0, 0, buf1, L, LL, L, 4);

        combined_att<<<NB * L, 256, 0, stream>>>(buf1, buf2, mask, conf, Sbv, Pb);

        // context_interact = cq + combined @ context_conv
        gemm_bf3<<<32 * 24, 256, 0, stream>>>(
            buf1, L, LL, cT, L, (long long)E * L,
            nullptr, nullptr, context_q, E, sE, context_int, E, sE, L, 6);

        pred3<<<(NB * L) / 4, 256, 0, stream>>>(context_int, E, E, Wds, bds, sentiment_pred, nullptr);
    } else {
        // ================= FALLBACK (round-2, proven) =================
        conv_mfma<<<dim3(F / 128, (NB * L) / 128), 256, 0, stream>>>(aspect_in, Wa, ba, aspect_int, F, 2 * F);
        conv_mfma<<<dim3(F / 128, (NB * L) / 128), 256, 0, stream>>>(opinion_in, Wo, bo, opinion_int, F, 2 * F);
        conv_mfma<<<dim3(E / 128, (NB * L) / 128), 256, 0, stream>>>(context_in, Wc, bc, context_conv, E, E);

        inv_l2norm<<<NB * L, 256, 0, stream>>>(aspect_int, F, 2 * F, inv_a);
        inv_l2norm<<<NB * L, 256, 0, stream>>>(opinion_int, F, 2 * F, inv_o);
        inv_l2norm<<<NB * L, 256, 0, stream>>>(context_conv, E, E, inv_c);

        gemm_nt<<<dim3(L / TBN, L / TBM, NB), 256, 0, stream>>>(
            aspect_int, 2 * F, sAO, opinion_int, 2 * F, sAO, buf1, L, LL, F, inv_a, inv_o);

        softmask_rows<<<NB * L, 256, 0, stream>>>(buf1, mask, buf2);
        colsum_denomO<<<dim3(L / 256, NB), 256, 0, stream>>>(buf1, mask, denomO);
        make_attO<<<dim3(L / 64, L / 64, NB), 256, 0, stream>>>(buf1, mask, denomO, buf3);

        gemm_nn<<<dim3(F / TBN, L / TBM, NB), 256, 0, stream>>>(
            buf2, L, LL, opinion_int, 2 * F, sAO, nullptr, 0, 0, aspect_int + F, 2 * F, sAO, L);
        gemm_nn<<<dim3(F / TBN, L / TBM, NB), 256, 0, stream>>>(
            buf3, L, LL, aspect_int, 2 * F, sAO, nullptr, 0, 0, opinion_int + F, 2 * F, sAO, L);

        pred3<<<(NB * L) / 4, 256, 0, stream>>>(aspect_int, 2 * F, 2 * F, Wda, bda, aspect_pred, nullptr);
        pred3<<<(NB * L) / 4, 256, 0, stream>>>(opinion_int, 2 * F, 2 * F, Wdo, bdo, opinion_pred, conf);

        colsum_pos<<<dim3(L / 256, NB), 256, 0, stream>>>(pos_att, Pb);
        rowsum_mask<<<NB, 256, 0, stream>>>(mask, Sbv);

        gemm_nt<<<dim3(L / TBN, L / TBM, NB), 256, 0, stream>>>(
            context_q, E, sE, context_conv, E, sE, buf3, L, LL, E, nullptr, inv_c);

        gemm_nn<<<dim3(L / TBN, L / TBM, NB), 256, 0, stream>>>(
            buf3, L, LL, pos_att, L, LL, nullptr, 0, 0, buf1, L, LL, L);

        combined_att<<<NB * L, 256, 0, stream>>>(buf1, buf2, mask, conf, Sbv, Pb);

        gemm_nn<<<dim3(E / TBN, L / TBM, NB), 256, 0, stream>>>(
            buf1, L, LL, context_conv, E, sE, context_q, E, sE, context_int, E, sE, L);

        pred3<<<(NB * L) / 4, 256, 0, stream>>>(context_int, E, E, Wds, bds, sentiment_pred, nullptr);
    }
}